// Round 8
// baseline (270.568 us; speedup 1.0000x reference)
//
#include <hip/hip_runtime.h>

#define N_NODES 50000
#define N_EDGES 800000
#define D 128
#define N_GRAPHS 256
#define N_CLASSES 16
#define NB_SCAN ((N_NODES + 255) / 256)  // 196

typedef unsigned short ushort_t;
typedef unsigned int uint_t;
typedef unsigned char uchar_t;
typedef __attribute__((ext_vector_type(8))) short bf16x8;
typedef __attribute__((ext_vector_type(4))) float f32x4;
typedef __attribute__((ext_vector_type(4))) int i32x4;

__device__ __forceinline__ float bf2f(uint_t u) {
  return __uint_as_float(u << 16);
}
__device__ __forceinline__ uint_t f2bf(float f) {
  uint_t x = __float_as_uint(f);
  return (x + 0x7fffu + ((x >> 16) & 1u)) >> 16;
}
__device__ __forceinline__ void add8(float* acc, uint4 v) {
  acc[0] += bf2f(v.x & 0xffffu);
  acc[1] += bf2f(v.x >> 16);
  acc[2] += bf2f(v.y & 0xffffu);
  acc[3] += bf2f(v.y >> 16);
  acc[4] += bf2f(v.z & 0xffffu);
  acc[5] += bf2f(v.z >> 16);
  acc[6] += bf2f(v.w & 0xffffu);
  acc[7] += bf2f(v.w >> 16);
}

// ---- edge histogram over dst; store each edge's rank within its bucket ----
__global__ void k_pre(const int* __restrict__ ei, int* __restrict__ deg,
                      uchar_t* __restrict__ rank) {
  int e = blockIdx.x * blockDim.x + threadIdx.x;
  if (e < N_EDGES) {
    int d = ei[N_EDGES + e];
    int r = atomicAdd(&deg[d], 1);
    rank[e] = (uchar_t)r;
  }
}

// ---- pack W (fp32 [128][128], k-major rows) into MFMA B-fragment order ----
__global__ __launch_bounds__(256) void k_wprep(const float* __restrict__ W1,
                                               const float* __restrict__ W2,
                                               uint4* __restrict__ W1f,
                                               uint4* __restrict__ W2f) {
  int slot = blockIdx.x * 256 + threadIdx.x;  // 0..4095
  const float* W = (slot < 2048) ? W1 : W2;
  uint4* Wf = (slot < 2048) ? W1f : W2f;
  int sl = slot & 2047;
  int lane = sl & 63;
  int s = (sl >> 6) & 3;
  int n = sl >> 8;
  int col = n * 16 + (lane & 15);
  int k0 = s * 32 + (lane >> 4) * 8;
  uint4 o;
  o.x = f2bf(W[(size_t)(k0 + 0) * D + col]) | (f2bf(W[(size_t)(k0 + 1) * D + col]) << 16);
  o.y = f2bf(W[(size_t)(k0 + 2) * D + col]) | (f2bf(W[(size_t)(k0 + 3) * D + col]) << 16);
  o.z = f2bf(W[(size_t)(k0 + 4) * D + col]) | (f2bf(W[(size_t)(k0 + 5) * D + col]) << 16);
  o.w = f2bf(W[(size_t)(k0 + 6) * D + col]) | (f2bf(W[(size_t)(k0 + 7) * D + col]) << 16);
  Wf[sl] = o;
}

// ---- block sums of PADDED deg (buckets padded to multiple of 4) + dinv ----
__global__ __launch_bounds__(256) void k_bsum(const int* __restrict__ deg,
                                              float* __restrict__ dinv,
                                              int* __restrict__ bsum) {
  int t = threadIdx.x;
  int i = blockIdx.x * 256 + t;
  int pd = 0;
  if (i < N_NODES) {
    int d = deg[i];
    dinv[i] = rsqrtf((float)(d + 1));
    pd = (d + 3) & ~3;
  }
#pragma unroll
  for (int o = 1; o < 64; o <<= 1) pd += __shfl_xor(pd, o);
  __shared__ int ws[4];
  if ((t & 63) == 0) ws[t >> 6] = pd;
  __syncthreads();
  if (t == 0) bsum[blockIdx.x] = ws[0] + ws[1] + ws[2] + ws[3];
}

// ---- scan the 196 partials (1 block) + per-graph 1/cnt via binary search ----
__global__ __launch_bounds__(256) void k_spart(const int* __restrict__ bsum,
                                               const int* __restrict__ batch,
                                               int* __restrict__ bpre,
                                               float* __restrict__ rcnts) {
  int t = threadIdx.x;
  int lane = t & 63, wid = t >> 6;
  int d = (t < NB_SCAN) ? bsum[t] : 0;
  int v = d;
#pragma unroll
  for (int o = 1; o < 64; o <<= 1) {
    int u = __shfl_up(v, o);
    if (lane >= o) v += u;
  }
  __shared__ int ws[4];
  __shared__ int bound[256];
  if (lane == 63) ws[wid] = v;
  {
    int g = t;
    int lo = 0, hi = N_NODES;
    while (lo < hi) {
      int m = (lo + hi) >> 1;
      if (batch[m] < g) lo = m + 1; else hi = m;
    }
    bound[g] = lo;
  }
  __syncthreads();
  int add = 0;
  for (int w = 0; w < wid; ++w) add += ws[w];
  if (t < NB_SCAN) bpre[t] = v - d + add;
  int cnt = ((t == 255) ? N_NODES : bound[t + 1]) - bound[t];
  rcnts[t] = 1.0f / (float)max(cnt, 1);
}

// ---- fill offsets (padded prefix) with in-block wave scan ----
__global__ __launch_bounds__(256) void k_fill(const int* __restrict__ deg,
                                              const int* __restrict__ bpre,
                                              int* __restrict__ offs) {
  int t = threadIdx.x;
  int i = blockIdx.x * 256 + t;
  int pd = (i < N_NODES) ? ((deg[i] + 3) & ~3) : 0;
  int lane = t & 63, wid = t >> 6;
  int v = pd;
#pragma unroll
  for (int o = 1; o < 64; o <<= 1) {
    int u = __shfl_up(v, o);
    if (lane >= o) v += u;
  }
  __shared__ int ws[4];
  if (lane == 63) ws[wid] = v;
  __syncthreads();
  int add = bpre[blockIdx.x];
  for (int w = 0; w < wid; ++w) add += ws[w];
  if (i < N_NODES) offs[i] = v - pd + add;
}

// ---- CSR fill, atomic-free: csr[offs[dst] + rank[e]] = src ----
__global__ void k_csr(const int* __restrict__ ei, const int* __restrict__ offs,
                      const uchar_t* __restrict__ rank, int* __restrict__ csr) {
  int e = blockIdx.x * blockDim.x + threadIdx.x;
  if (e >= N_EDGES) return;
  int s = ei[e];
  int d = ei[N_EDGES + e];
  __builtin_nontemporal_store(s, csr + offs[d] + (int)rank[e]);
}

// ---- MFMA GEMM: [N x 128] @ [128 x 128], epilogue scales row r by dinv[r] ----
template <typename TIN>
__global__ __launch_bounds__(256) void k_gemm_mfma(const TIN* __restrict__ A,
                                                   const uint4* __restrict__ Wf,
                                                   const float* __restrict__ dinv,
                                                   ushort_t* __restrict__ Out) {
  int t = threadIdx.x;
  int wv = t >> 6, lane = t & 63;
  int row16 = lane & 15, chunk = lane >> 4;  // chunk 0..3
  int row0 = blockIdx.x * 64 + wv * 16;
  int arow = row0 + row16;
  if (arow >= N_NODES) arow = 0;  // stores are guarded
  bf16x8 afrag[4];
  if constexpr (sizeof(TIN) == 4) {  // fp32 input
    const float* Ar = A + (size_t)arow * D + chunk * 8;
#pragma unroll
    for (int s = 0; s < 4; ++s) {
      float4 lo = *(const float4*)(Ar + s * 32);
      float4 hi = *(const float4*)(Ar + s * 32 + 4);
      uint4 u;
      u.x = f2bf(lo.x) | (f2bf(lo.y) << 16);
      u.y = f2bf(lo.z) | (f2bf(lo.w) << 16);
      u.z = f2bf(hi.x) | (f2bf(hi.y) << 16);
      u.w = f2bf(hi.z) | (f2bf(hi.w) << 16);
      afrag[s] = *(bf16x8*)&u;
    }
  } else {  // bf16 input
    const ushort_t* Ar = A + (size_t)arow * D + chunk * 8;
#pragma unroll
    for (int s = 0; s < 4; ++s) afrag[s] = *(const bf16x8*)(Ar + s * 32);
  }
  f32x4 acc[8];
#pragma unroll
  for (int n = 0; n < 8; ++n) acc[n] = (f32x4){0.f, 0.f, 0.f, 0.f};
  const bf16x8* Wb = (const bf16x8*)Wf;
#pragma unroll
  for (int n = 0; n < 8; ++n) {
#pragma unroll
    for (int s = 0; s < 4; ++s) {
      bf16x8 b = Wb[(n * 4 + s) * 64 + lane];
      acc[n] = __builtin_amdgcn_mfma_f32_16x16x32_bf16(afrag[s], b, acc[n], 0, 0, 0);
    }
  }
  int crow0 = row0 + chunk * 4;  // C/D: col=lane&15, row=(lane>>4)*4+reg
  float dv[4];
#pragma unroll
  for (int j = 0; j < 4; ++j)
    dv[j] = (crow0 + j < N_NODES) ? dinv[crow0 + j] : 0.f;
#pragma unroll
  for (int n = 0; n < 8; ++n) {
#pragma unroll
    for (int j = 0; j < 4; ++j) {
      int r = crow0 + j;
      if (r < N_NODES)
        Out[(size_t)r * D + n * 16 + row16] = (ushort_t)f2bf(acc[n][j] * dv[j]);
    }
  }
}

// ---- edge loop: wave per node, 16 edges/iter (4 groups x i32x4 of srcs) ----
__device__ __forceinline__ void agg_core(const ushort_t* __restrict__ h,
                                         const int* __restrict__ csr,
                                         int beg, int end, int grp, int d0,
                                         float* acc) {
  for (int wb = beg; wb < end; wb += 16) {
    int i0 = wb + grp * 4;  // beg%4==0 -> 16B-aligned
    i32x4 s4 = __builtin_nontemporal_load((const i32x4*)(csr + i0));
    bool b0 = i0 < end, b1 = i0 + 1 < end, b2 = i0 + 2 < end, b3 = i0 + 3 < end;
    uint4 v0, v1, v2, v3;
    if (b0) v0 = *(const uint4*)(h + (size_t)s4.x * D + d0);
    if (b1) v1 = *(const uint4*)(h + (size_t)s4.y * D + d0);
    if (b2) v2 = *(const uint4*)(h + (size_t)s4.z * D + d0);
    if (b3) v3 = *(const uint4*)(h + (size_t)s4.w * D + d0);
    if (b0) add8(acc, v0);
    if (b1) add8(acc, v1);
    if (b2) add8(acc, v2);
    if (b3) add8(acc, v3);
  }
}

// ---- agg layer1: wave per node; out = relu(dinv[n]*(sum+self) + b1) -> bf16 ----
__global__ __launch_bounds__(256) void k_agg_relu(const ushort_t* __restrict__ h,
                                                  const int* __restrict__ csr,
                                                  const int* __restrict__ offs,
                                                  const int* __restrict__ deg,
                                                  const float* __restrict__ dinv,
                                                  const float* __restrict__ bias,
                                                  ushort_t* __restrict__ obf) {
  int t = threadIdx.x;
  int wv = t >> 6, lane = t & 63;
  int grp = lane >> 4, gl = lane & 15;
  int d0 = gl * 8;
  int node = blockIdx.x * 4 + wv;  // N_NODES % 4 == 0
  int beg = offs[node], end = beg + deg[node];
  float acc[8] = {0.f, 0.f, 0.f, 0.f, 0.f, 0.f, 0.f, 0.f};
  agg_core(h, csr, beg, end, grp, d0, acc);
#pragma unroll
  for (int m = 16; m <= 32; m <<= 1) {
#pragma unroll
    for (int i = 0; i < 8; ++i) acc[i] += __shfl_xor(acc[i], m);
  }
  if (grp == 0) {
    uint4 v = *(const uint4*)(h + (size_t)node * D + d0);  // self h'
    add8(acc, v);
    float sc = dinv[node];
    float4 blo = *(const float4*)(bias + d0);
    float4 bhi = *(const float4*)(bias + d0 + 4);
    acc[0] = fmaf(acc[0], sc, blo.x);
    acc[1] = fmaf(acc[1], sc, blo.y);
    acc[2] = fmaf(acc[2], sc, blo.z);
    acc[3] = fmaf(acc[3], sc, blo.w);
    acc[4] = fmaf(acc[4], sc, bhi.x);
    acc[5] = fmaf(acc[5], sc, bhi.y);
    acc[6] = fmaf(acc[6], sc, bhi.z);
    acc[7] = fmaf(acc[7], sc, bhi.w);
#pragma unroll
    for (int i = 0; i < 8; ++i) acc[i] = fmaxf(acc[i], 0.f);
    uint4 o;
    o.x = f2bf(acc[0]) | (f2bf(acc[1]) << 16);
    o.y = f2bf(acc[2]) | (f2bf(acc[3]) << 16);
    o.z = f2bf(acc[4]) | (f2bf(acc[5]) << 16);
    o.w = f2bf(acc[6]) | (f2bf(acc[7]) << 16);
    *(uint4*)(obf + (size_t)node * D + d0) = o;
  }
}

// ---- agg layer2 + mean-pool: sums[g] += dinv[n]*(sum+self)/cnt[g] ----
// 4 waves/block, each wave 4 sequential nodes (block = 16 nodes).
__global__ __launch_bounds__(256) void k_agg_pool(const ushort_t* __restrict__ h,
                                                   const int* __restrict__ csr,
                                                   const int* __restrict__ offs,
                                                   const int* __restrict__ deg,
                                                   const float* __restrict__ dinv,
                                                   const int* __restrict__ batch,
                                                   const float* __restrict__ rcnts,
                                                   float* __restrict__ sums) {
  __shared__ float pool[128];
  int t = threadIdx.x;
  int wv = t >> 6, lane = t & 63;
  int grp = lane >> 4, gl = lane & 15;
  int d0 = gl * 8;
  int node0 = blockIdx.x * 16;  // N_NODES % 16 == 0
  int g0 = batch[node0];
  if (t < 128) pool[t] = 0.f;
  __syncthreads();
  float pacc[8] = {0.f, 0.f, 0.f, 0.f, 0.f, 0.f, 0.f, 0.f};
  for (int i = 0; i < 4; ++i) {
    int node = node0 + wv * 4 + i;
    int beg = offs[node], end = beg + deg[node];
    float acc[8] = {0.f, 0.f, 0.f, 0.f, 0.f, 0.f, 0.f, 0.f};
    agg_core(h, csr, beg, end, grp, d0, acc);
#pragma unroll
    for (int m = 16; m <= 32; m <<= 1) {
#pragma unroll
      for (int k = 0; k < 8; ++k) acc[k] += __shfl_xor(acc[k], m);
    }
    if (grp == 0) {
      uint4 v = *(const uint4*)(h + (size_t)node * D + d0);  // self h'
      add8(acc, v);
      int g = batch[node];
      float sc = dinv[node] * rcnts[g];
      if (g == g0) {
#pragma unroll
        for (int k = 0; k < 8; ++k) pacc[k] = fmaf(acc[k], sc, pacc[k]);
      } else {
#pragma unroll
        for (int k = 0; k < 8; ++k)
          atomicAdd(&sums[(size_t)g * D + d0 + k], acc[k] * sc);
      }
    }
  }
  if (grp == 0) {
#pragma unroll
    for (int k = 0; k < 8; ++k) atomicAdd(&pool[d0 + k], pacc[k]);
  }
  __syncthreads();
  if (t < 128) atomicAdd(&sums[(size_t)g0 * D + t], pool[t]);
}

// ---- mean(+b2) + final linear head ----
__global__ __launch_bounds__(128) void k_final(const float* __restrict__ sums,
                                               const float* __restrict__ b2,
                                               const float* __restrict__ Wc,
                                               const float* __restrict__ bc,
                                               float* __restrict__ out) {
  __shared__ float p[128];
  int g = blockIdx.x;
  int t = threadIdx.x;
  p[t] = sums[g * D + t] + b2[t];
  __syncthreads();
  if (t < N_CLASSES) {
    float acc = bc[t];
    for (int k = 0; k < D; ++k) acc = fmaf(p[k], Wc[k * N_CLASSES + t], acc);
    out[g * N_CLASSES + t] = acc;
  }
}

extern "C" void kernel_launch(void* const* d_in, const int* in_sizes, int n_in,
                              void* d_out, int out_size, void* d_ws, size_t ws_size,
                              hipStream_t stream) {
  const float* x = (const float*)d_in[0];
  const int* ei = (const int*)d_in[1];
  const int* batch = (const int*)d_in[2];
  const float* W1 = (const float*)d_in[3];
  const float* b1 = (const float*)d_in[4];
  const float* W2 = (const float*)d_in[5];
  const float* b2 = (const float*)d_in[6];
  const float* Wc = (const float*)d_in[7];
  const float* bc = (const float*)d_in[8];
  float* out = (float*)d_out;

  char* ws = (char*)d_ws;
  size_t off = 0;
  auto alloc = [&](size_t bytes) -> void* {
    void* p = (void*)(ws + off);
    off += (bytes + 255) & ~(size_t)255;
    return p;
  };
  // zero-init region: deg, sums contiguous at the front
  int* deg = (int*)alloc((size_t)N_NODES * 4);
  float* sums = (float*)alloc((size_t)N_GRAPHS * D * 4);
  size_t zero_bytes = off;
  int* offs = (int*)alloc((size_t)N_NODES * 4);
  float* dinv = (float*)alloc((size_t)N_NODES * 4);
  float* rcnts = (float*)alloc((size_t)N_GRAPHS * 4);
  int* bsum = (int*)alloc((size_t)NB_SCAN * 4);
  int* bpre = (int*)alloc((size_t)NB_SCAN * 4);
  uchar_t* rank = (uchar_t*)alloc((size_t)N_EDGES);
  uint4* W1f = (uint4*)alloc((size_t)2048 * 16);
  uint4* W2f = (uint4*)alloc((size_t)2048 * 16);
  // padded CSR: buckets rounded to 4 entries (+16 slack for i32x4 overread)
  int* csr = (int*)alloc(((size_t)N_EDGES + 3 * N_NODES + 16) * 4);
  ushort_t* hbuf = (ushort_t*)alloc((size_t)N_NODES * D * 2);  // h' (bf16)
  ushort_t* x2 = (ushort_t*)alloc((size_t)N_NODES * D * 2);    // relu out bf16

  hipMemsetAsync(ws, 0, zero_bytes, stream);

  k_pre<<<(N_EDGES + 255) / 256, 256, 0, stream>>>(ei, deg, rank);
  k_wprep<<<16, 256, 0, stream>>>(W1, W2, W1f, W2f);
  k_bsum<<<NB_SCAN, 256, 0, stream>>>(deg, dinv, bsum);
  k_spart<<<1, 256, 0, stream>>>(bsum, batch, bpre, rcnts);
  k_fill<<<NB_SCAN, 256, 0, stream>>>(deg, bpre, offs);
  k_csr<<<(N_EDGES + 255) / 256, 256, 0, stream>>>(ei, offs, rank, csr);

  k_gemm_mfma<float><<<(N_NODES + 63) / 64, 256, 0, stream>>>(x, W1f, dinv, hbuf);
  k_agg_relu<<<N_NODES / 4, 256, 0, stream>>>(hbuf, csr, offs, deg, dinv, b1, x2);
  k_gemm_mfma<ushort_t><<<(N_NODES + 63) / 64, 256, 0, stream>>>(x2, W2f, dinv, hbuf);
  k_agg_pool<<<N_NODES / 16, 256, 0, stream>>>(hbuf, csr, offs, deg, dinv, batch, rcnts, sums);

  k_final<<<N_GRAPHS, 128, 0, stream>>>(sums, b2, Wc, bc, out);
}

// Round 9
// 267.687 us; speedup vs baseline: 1.0108x; 1.0108x over previous
//
#include <hip/hip_runtime.h>

#define N_NODES 50000
#define N_EDGES 800000
#define D 128
#define N_GRAPHS 256
#define N_CLASSES 16
#define NB_SCAN ((N_NODES + 255) / 256)  // 196

typedef unsigned short ushort_t;
typedef unsigned int uint_t;
typedef unsigned char uchar_t;
typedef __attribute__((ext_vector_type(8))) short bf16x8;
typedef __attribute__((ext_vector_type(4))) float f32x4;
typedef __attribute__((ext_vector_type(4))) int i32x4;

__device__ __forceinline__ float bf2f(uint_t u) {
  return __uint_as_float(u << 16);
}
__device__ __forceinline__ uint_t f2bf(float f) {
  uint_t x = __float_as_uint(f);
  return (x + 0x7fffu + ((x >> 16) & 1u)) >> 16;
}
__device__ __forceinline__ void add8(float* acc, uint4 v) {
  acc[0] += bf2f(v.x & 0xffffu);
  acc[1] += bf2f(v.x >> 16);
  acc[2] += bf2f(v.y & 0xffffu);
  acc[3] += bf2f(v.y >> 16);
  acc[4] += bf2f(v.z & 0xffffu);
  acc[5] += bf2f(v.z >> 16);
  acc[6] += bf2f(v.w & 0xffffu);
  acc[7] += bf2f(v.w >> 16);
}

// ---- edge histogram over dst; store each edge's rank within its bucket ----
__global__ void k_pre(const int* __restrict__ ei, int* __restrict__ deg,
                      uchar_t* __restrict__ rank) {
  int e = blockIdx.x * blockDim.x + threadIdx.x;
  if (e < N_EDGES) {
    int d = ei[N_EDGES + e];
    int r = atomicAdd(&deg[d], 1);
    rank[e] = (uchar_t)r;
  }
}

// ---- fused: blocks [0,NB_SCAN): padded-deg block sums + dinv;
//             blocks [NB_SCAN, NB_SCAN+16): W-fragment packing ----
__global__ __launch_bounds__(256) void k_bsum(const int* __restrict__ deg,
                                              float* __restrict__ dinv,
                                              int* __restrict__ bsum,
                                              const float* __restrict__ W1,
                                              const float* __restrict__ W2,
                                              uint4* __restrict__ W1f,
                                              uint4* __restrict__ W2f) {
  int t = threadIdx.x;
  if (blockIdx.x >= NB_SCAN) {  // W-prep path
    int slot = (blockIdx.x - NB_SCAN) * 256 + t;  // 0..4095
    const float* W = (slot < 2048) ? W1 : W2;
    uint4* Wf = (slot < 2048) ? W1f : W2f;
    int sl = slot & 2047;
    int lane = sl & 63;
    int s = (sl >> 6) & 3;
    int n = sl >> 8;
    int col = n * 16 + (lane & 15);
    int k0 = s * 32 + (lane >> 4) * 8;
    uint4 o;
    o.x = f2bf(W[(size_t)(k0 + 0) * D + col]) | (f2bf(W[(size_t)(k0 + 1) * D + col]) << 16);
    o.y = f2bf(W[(size_t)(k0 + 2) * D + col]) | (f2bf(W[(size_t)(k0 + 3) * D + col]) << 16);
    o.z = f2bf(W[(size_t)(k0 + 4) * D + col]) | (f2bf(W[(size_t)(k0 + 5) * D + col]) << 16);
    o.w = f2bf(W[(size_t)(k0 + 6) * D + col]) | (f2bf(W[(size_t)(k0 + 7) * D + col]) << 16);
    Wf[sl] = o;
    return;
  }
  int i = blockIdx.x * 256 + t;
  int pd = 0;
  if (i < N_NODES) {
    int d = deg[i];
    dinv[i] = rsqrtf((float)(d + 1));
    pd = (d + 3) & ~3;
  }
#pragma unroll
  for (int o = 1; o < 64; o <<= 1) pd += __shfl_xor(pd, o);
  __shared__ int ws[4];
  if ((t & 63) == 0) ws[t >> 6] = pd;
  __syncthreads();
  if (t == 0) bsum[blockIdx.x] = ws[0] + ws[1] + ws[2] + ws[3];
}

// ---- scan the 196 partials (1 block) + per-graph 1/cnt via binary search ----
__global__ __launch_bounds__(256) void k_spart(const int* __restrict__ bsum,
                                               const int* __restrict__ batch,
                                               int* __restrict__ bpre,
                                               float* __restrict__ rcnts) {
  int t = threadIdx.x;
  int lane = t & 63, wid = t >> 6;
  int d = (t < NB_SCAN) ? bsum[t] : 0;
  int v = d;
#pragma unroll
  for (int o = 1; o < 64; o <<= 1) {
    int u = __shfl_up(v, o);
    if (lane >= o) v += u;
  }
  __shared__ int ws[4];
  __shared__ int bound[256];
  if (lane == 63) ws[wid] = v;
  {
    int g = t;
    int lo = 0, hi = N_NODES;
    while (lo < hi) {
      int m = (lo + hi) >> 1;
      if (batch[m] < g) lo = m + 1; else hi = m;
    }
    bound[g] = lo;
  }
  __syncthreads();
  int add = 0;
  for (int w = 0; w < wid; ++w) add += ws[w];
  if (t < NB_SCAN) bpre[t] = v - d + add;
  int cnt = ((t == 255) ? N_NODES : bound[t + 1]) - bound[t];
  rcnts[t] = 1.0f / (float)max(cnt, 1);
}

// ---- fill offsets (padded prefix) with in-block wave scan ----
__global__ __launch_bounds__(256) void k_fill(const int* __restrict__ deg,
                                              const int* __restrict__ bpre,
                                              int* __restrict__ offs) {
  int t = threadIdx.x;
  int i = blockIdx.x * 256 + t;
  int pd = (i < N_NODES) ? ((deg[i] + 3) & ~3) : 0;
  int lane = t & 63, wid = t >> 6;
  int v = pd;
#pragma unroll
  for (int o = 1; o < 64; o <<= 1) {
    int u = __shfl_up(v, o);
    if (lane >= o) v += u;
  }
  __shared__ int ws[4];
  if (lane == 63) ws[wid] = v;
  __syncthreads();
  int add = bpre[blockIdx.x];
  for (int w = 0; w < wid; ++w) add += ws[w];
  if (i < N_NODES) offs[i] = v - pd + add;
}

// ---- CSR fill, atomic-free: csr[offs[dst] + rank[e]] = src ----
__global__ void k_csr(const int* __restrict__ ei, const int* __restrict__ offs,
                      const uchar_t* __restrict__ rank, int* __restrict__ csr) {
  int e = blockIdx.x * blockDim.x + threadIdx.x;
  if (e >= N_EDGES) return;
  int s = ei[e];
  int d = ei[N_EDGES + e];
  __builtin_nontemporal_store(s, csr + offs[d] + (int)rank[e]);
}

// ---- MFMA GEMM: [N x 128] @ [128 x 128], LDS-staged A (XOR-swizzled),
//      epilogue scales row r by dinv[r]. Block = 256 thr = 64 rows. ----
template <typename TIN>
__global__ __launch_bounds__(256) void k_gemm_mfma(const TIN* __restrict__ A,
                                                   const uint4* __restrict__ Wf,
                                                   const float* __restrict__ dinv,
                                                   ushort_t* __restrict__ Out) {
  __shared__ uint4 As[1024];  // 64 rows x 16 granules (16B = 8 bf16), swizzled
  int t = threadIdx.x;
  int row0 = blockIdx.x * 64;
  if constexpr (sizeof(TIN) == 4) {  // fp32 input: 2048 float4s, coalesced
    uint2* As2 = (uint2*)As;
#pragma unroll
    for (int i = 0; i < 8; ++i) {
      int F = t + 256 * i;      // float4 id
      int r = F >> 5, f = F & 31;
      int grow = row0 + r;
      uint2 u = make_uint2(0, 0);
      if (grow < N_NODES) {
        float4 v = *(const float4*)(A + (size_t)grow * D + f * 4);
        u.x = f2bf(v.x) | (f2bf(v.y) << 16);
        u.y = f2bf(v.z) | (f2bf(v.w) << 16);
      }
      int g = f >> 1;
      As2[(r * 16 + (g ^ (r & 7))) * 2 + (f & 1)] = u;
    }
  } else {  // bf16 input: 1024 granules, coalesced 16B loads
#pragma unroll
    for (int i = 0; i < 4; ++i) {
      int G = t + 256 * i;      // granule id
      int r = G >> 4, g = G & 15;
      int grow = row0 + r;
      uint4 u = make_uint4(0, 0, 0, 0);
      if (grow < N_NODES) u = *(const uint4*)(A + (size_t)grow * D + g * 8);
      As[r * 16 + (g ^ (r & 7))] = u;
    }
  }
  __syncthreads();
  int wv = t >> 6, lane = t & 63;
  int row16 = lane & 15, chunk = lane >> 4;  // chunk 0..3
  int rl = wv * 16 + row16;
  bf16x8 afrag[4];
#pragma unroll
  for (int s = 0; s < 4; ++s) {
    int g = s * 4 + chunk;
    afrag[s] = *(const bf16x8*)&As[rl * 16 + (g ^ (rl & 7))];
  }
  f32x4 acc[8];
#pragma unroll
  for (int n = 0; n < 8; ++n) acc[n] = (f32x4){0.f, 0.f, 0.f, 0.f};
  const bf16x8* Wb = (const bf16x8*)Wf;
#pragma unroll
  for (int n = 0; n < 8; ++n) {
#pragma unroll
    for (int s = 0; s < 4; ++s) {
      bf16x8 b = Wb[(n * 4 + s) * 64 + lane];
      acc[n] = __builtin_amdgcn_mfma_f32_16x16x32_bf16(afrag[s], b, acc[n], 0, 0, 0);
    }
  }
  int row0w = row0 + wv * 16;
  int crow0 = row0w + chunk * 4;  // C/D: col=lane&15, row=(lane>>4)*4+reg
  float dv[4];
#pragma unroll
  for (int j = 0; j < 4; ++j)
    dv[j] = (crow0 + j < N_NODES) ? dinv[crow0 + j] : 0.f;
#pragma unroll
  for (int n = 0; n < 8; ++n) {
#pragma unroll
    for (int j = 0; j < 4; ++j) {
      int r = crow0 + j;
      if (r < N_NODES)
        Out[(size_t)r * D + n * 16 + row16] = (ushort_t)f2bf(acc[n][j] * dv[j]);
    }
  }
}

// ---- edge loop: wave per node, 16 edges/iter (4 groups x i32x4 of srcs) ----
__device__ __forceinline__ void agg_core(const ushort_t* __restrict__ h,
                                         const int* __restrict__ csr,
                                         int beg, int end, int grp, int d0,
                                         float* acc) {
  for (int wb = beg; wb < end; wb += 16) {
    int i0 = wb + grp * 4;  // beg%4==0 -> 16B-aligned
    i32x4 s4 = __builtin_nontemporal_load((const i32x4*)(csr + i0));
    bool b0 = i0 < end, b1 = i0 + 1 < end, b2 = i0 + 2 < end, b3 = i0 + 3 < end;
    uint4 v0, v1, v2, v3;
    if (b0) v0 = *(const uint4*)(h + (size_t)s4.x * D + d0);
    if (b1) v1 = *(const uint4*)(h + (size_t)s4.y * D + d0);
    if (b2) v2 = *(const uint4*)(h + (size_t)s4.z * D + d0);
    if (b3) v3 = *(const uint4*)(h + (size_t)s4.w * D + d0);
    if (b0) add8(acc, v0);
    if (b1) add8(acc, v1);
    if (b2) add8(acc, v2);
    if (b3) add8(acc, v3);
  }
}

// ---- agg layer1: wave per node; out = relu(dinv[n]*(sum+self) + b1) -> bf16 ----
__global__ __launch_bounds__(256) void k_agg_relu(const ushort_t* __restrict__ h,
                                                  const int* __restrict__ csr,
                                                  const int* __restrict__ offs,
                                                  const int* __restrict__ deg,
                                                  const float* __restrict__ dinv,
                                                  const float* __restrict__ bias,
                                                  ushort_t* __restrict__ obf) {
  int t = threadIdx.x;
  int wv = t >> 6, lane = t & 63;
  int grp = lane >> 4, gl = lane & 15;
  int d0 = gl * 8;
  int node = blockIdx.x * 4 + wv;  // N_NODES % 4 == 0
  int beg = offs[node], end = beg + deg[node];
  float acc[8] = {0.f, 0.f, 0.f, 0.f, 0.f, 0.f, 0.f, 0.f};
  agg_core(h, csr, beg, end, grp, d0, acc);
#pragma unroll
  for (int m = 16; m <= 32; m <<= 1) {
#pragma unroll
    for (int i = 0; i < 8; ++i) acc[i] += __shfl_xor(acc[i], m);
  }
  if (grp == 0) {
    uint4 v = *(const uint4*)(h + (size_t)node * D + d0);  // self h'
    add8(acc, v);
    float sc = dinv[node];
    float4 blo = *(const float4*)(bias + d0);
    float4 bhi = *(const float4*)(bias + d0 + 4);
    acc[0] = fmaf(acc[0], sc, blo.x);
    acc[1] = fmaf(acc[1], sc, blo.y);
    acc[2] = fmaf(acc[2], sc, blo.z);
    acc[3] = fmaf(acc[3], sc, blo.w);
    acc[4] = fmaf(acc[4], sc, bhi.x);
    acc[5] = fmaf(acc[5], sc, bhi.y);
    acc[6] = fmaf(acc[6], sc, bhi.z);
    acc[7] = fmaf(acc[7], sc, bhi.w);
#pragma unroll
    for (int i = 0; i < 8; ++i) acc[i] = fmaxf(acc[i], 0.f);
    uint4 o;
    o.x = f2bf(acc[0]) | (f2bf(acc[1]) << 16);
    o.y = f2bf(acc[2]) | (f2bf(acc[3]) << 16);
    o.z = f2bf(acc[4]) | (f2bf(acc[5]) << 16);
    o.w = f2bf(acc[6]) | (f2bf(acc[7]) << 16);
    *(uint4*)(obf + (size_t)node * D + d0) = o;
  }
}

// ---- agg layer2 + mean-pool: block = 1024 thr = 16 waves, wave per node.
// Per-wave LDS row + tree sum; one global atomic set per block. ----
__global__ __launch_bounds__(1024) void k_agg_pool(const ushort_t* __restrict__ h,
                                                   const int* __restrict__ csr,
                                                   const int* __restrict__ offs,
                                                   const int* __restrict__ deg,
                                                   const float* __restrict__ dinv,
                                                   const int* __restrict__ batch,
                                                   const float* __restrict__ rcnts,
                                                   float* __restrict__ sums) {
  __shared__ float pool2[16][128];  // 8 KB
  int t = threadIdx.x;
  int wv = t >> 6, lane = t & 63;
  int grp = lane >> 4, gl = lane & 15;
  int d0 = gl * 8;
  int node0 = blockIdx.x * 16;  // N_NODES % 16 == 0
  int node = node0 + wv;
  int g0 = batch[node0];
  int beg = offs[node], end = beg + deg[node];
  float acc[8] = {0.f, 0.f, 0.f, 0.f, 0.f, 0.f, 0.f, 0.f};
  agg_core(h, csr, beg, end, grp, d0, acc);
#pragma unroll
  for (int m = 16; m <= 32; m <<= 1) {
#pragma unroll
    for (int k = 0; k < 8; ++k) acc[k] += __shfl_xor(acc[k], m);
  }
  if (grp == 0) {
    uint4 v = *(const uint4*)(h + (size_t)node * D + d0);  // self h'
    add8(acc, v);
    int g = batch[node];
    float sc = dinv[node] * rcnts[g];
    if (g == g0) {
#pragma unroll
      for (int k = 0; k < 8; ++k) pool2[wv][d0 + k] = acc[k] * sc;
    } else {
#pragma unroll
      for (int k = 0; k < 8; ++k) {
        pool2[wv][d0 + k] = 0.f;
        atomicAdd(&sums[(size_t)g * D + d0 + k], acc[k] * sc);
      }
    }
  }
  __syncthreads();
  if (t < 128) {
    float s = 0.f;
#pragma unroll
    for (int w = 0; w < 16; ++w) s += pool2[w][t];
    atomicAdd(&sums[(size_t)g0 * D + t], s);
  }
}

// ---- mean(+b2) + final linear head ----
__global__ __launch_bounds__(128) void k_final(const float* __restrict__ sums,
                                               const float* __restrict__ b2,
                                               const float* __restrict__ Wc,
                                               const float* __restrict__ bc,
                                               float* __restrict__ out) {
  __shared__ float p[128];
  int g = blockIdx.x;
  int t = threadIdx.x;
  p[t] = sums[g * D + t] + b2[t];
  __syncthreads();
  if (t < N_CLASSES) {
    float acc = bc[t];
    for (int k = 0; k < D; ++k) acc = fmaf(p[k], Wc[k * N_CLASSES + t], acc);
    out[g * N_CLASSES + t] = acc;
  }
}

extern "C" void kernel_launch(void* const* d_in, const int* in_sizes, int n_in,
                              void* d_out, int out_size, void* d_ws, size_t ws_size,
                              hipStream_t stream) {
  const float* x = (const float*)d_in[0];
  const int* ei = (const int*)d_in[1];
  const int* batch = (const int*)d_in[2];
  const float* W1 = (const float*)d_in[3];
  const float* b1 = (const float*)d_in[4];
  const float* W2 = (const float*)d_in[5];
  const float* b2 = (const float*)d_in[6];
  const float* Wc = (const float*)d_in[7];
  const float* bc = (const float*)d_in[8];
  float* out = (float*)d_out;

  char* ws = (char*)d_ws;
  size_t off = 0;
  auto alloc = [&](size_t bytes) -> void* {
    void* p = (void*)(ws + off);
    off += (bytes + 255) & ~(size_t)255;
    return p;
  };
  // zero-init region: deg, sums contiguous at the front
  int* deg = (int*)alloc((size_t)N_NODES * 4);
  float* sums = (float*)alloc((size_t)N_GRAPHS * D * 4);
  size_t zero_bytes = off;
  int* offs = (int*)alloc((size_t)N_NODES * 4);
  float* dinv = (float*)alloc((size_t)N_NODES * 4);
  float* rcnts = (float*)alloc((size_t)N_GRAPHS * 4);
  int* bsum = (int*)alloc((size_t)NB_SCAN * 4);
  int* bpre = (int*)alloc((size_t)NB_SCAN * 4);
  uchar_t* rank = (uchar_t*)alloc((size_t)N_EDGES);
  uint4* W1f = (uint4*)alloc((size_t)2048 * 16);
  uint4* W2f = (uint4*)alloc((size_t)2048 * 16);
  // padded CSR: buckets rounded to 4 entries (+16 slack for i32x4 overread)
  int* csr = (int*)alloc(((size_t)N_EDGES + 3 * N_NODES + 16) * 4);
  ushort_t* hbuf = (ushort_t*)alloc((size_t)N_NODES * D * 2);  // h' (bf16)
  ushort_t* x2 = (ushort_t*)alloc((size_t)N_NODES * D * 2);    // relu out bf16

  hipMemsetAsync(ws, 0, zero_bytes, stream);

  k_pre<<<(N_EDGES + 255) / 256, 256, 0, stream>>>(ei, deg, rank);
  k_bsum<<<NB_SCAN + 16, 256, 0, stream>>>(deg, dinv, bsum, W1, W2, W1f, W2f);
  k_spart<<<1, 256, 0, stream>>>(bsum, batch, bpre, rcnts);
  k_fill<<<NB_SCAN, 256, 0, stream>>>(deg, bpre, offs);
  k_csr<<<(N_EDGES + 255) / 256, 256, 0, stream>>>(ei, offs, rank, csr);

  k_gemm_mfma<float><<<(N_NODES + 63) / 64, 256, 0, stream>>>(x, W1f, dinv, hbuf);
  k_agg_relu<<<N_NODES / 4, 256, 0, stream>>>(hbuf, csr, offs, deg, dinv, b1, x2);
  k_gemm_mfma<ushort_t><<<(N_NODES + 63) / 64, 256, 0, stream>>>(x2, W2f, dinv, hbuf);
  k_agg_pool<<<N_NODES / 16, 1024, 0, stream>>>(hbuf, csr, offs, deg, dinv, batch, rcnts, sums);

  k_final<<<N_GRAPHS, 128, 0, stream>>>(sums, b2, Wc, bc, out);
}

// Round 10
// 249.443 us; speedup vs baseline: 1.0847x; 1.0731x over previous
//
#include <hip/hip_runtime.h>

#define N_NODES 50000
#define N_EDGES 800000
#define D 128
#define N_GRAPHS 256
#define N_CLASSES 16
#define NB_DINV ((N_NODES + 255) / 256)  // 196
#define BKT 64                           // CSR bucket slots per node

typedef unsigned short ushort_t;
typedef unsigned int uint_t;
typedef unsigned char uchar_t;
typedef __attribute__((ext_vector_type(8))) short bf16x8;
typedef __attribute__((ext_vector_type(4))) float f32x4;
typedef __attribute__((ext_vector_type(4))) int i32x4;

__device__ __forceinline__ float bf2f(uint_t u) {
  return __uint_as_float(u << 16);
}
__device__ __forceinline__ uint_t f2bf(float f) {
  uint_t x = __float_as_uint(f);
  return (x + 0x7fffu + ((x >> 16) & 1u)) >> 16;
}
__device__ __forceinline__ void add8(float* acc, uint4 v) {
  acc[0] += bf2f(v.x & 0xffffu);
  acc[1] += bf2f(v.x >> 16);
  acc[2] += bf2f(v.y & 0xffffu);
  acc[3] += bf2f(v.y >> 16);
  acc[4] += bf2f(v.z & 0xffffu);
  acc[5] += bf2f(v.z >> 16);
  acc[6] += bf2f(v.w & 0xffffu);
  acc[7] += bf2f(v.w >> 16);
}

// ---- histogram + direct-bucket CSR in one pass ----
// rank r returned by the atomic gives the slot: csr[d*BKT + r] = s.
__global__ void k_pre(const int* __restrict__ ei, int* __restrict__ deg,
                      int* __restrict__ csr) {
  int e = blockIdx.x * blockDim.x + threadIdx.x;
  if (e >= N_EDGES) return;
  int s = ei[e];
  int d = ei[N_EDGES + e];
  int r = atomicAdd(&deg[d], 1);
  if (r < BKT) __builtin_nontemporal_store(s, csr + d * BKT + r);
}

// ---- fused prep: dinv | W-fragment packing | per-graph 1/cnt ----
__global__ __launch_bounds__(256) void k_prep(const int* __restrict__ deg,
                                              float* __restrict__ dinv,
                                              const float* __restrict__ W1,
                                              const float* __restrict__ W2,
                                              uint4* __restrict__ W1f,
                                              uint4* __restrict__ W2f,
                                              const int* __restrict__ batch,
                                              float* __restrict__ rcnts) {
  int t = threadIdx.x;
  int b = blockIdx.x;
  if (b < NB_DINV) {  // dinv path
    int i = b * 256 + t;
    if (i < N_NODES) dinv[i] = rsqrtf((float)(deg[i] + 1));
    return;
  }
  if (b < NB_DINV + 16) {  // W-prep path
    int slot = (b - NB_DINV) * 256 + t;  // 0..4095
    const float* W = (slot < 2048) ? W1 : W2;
    uint4* Wf = (slot < 2048) ? W1f : W2f;
    int sl = slot & 2047;
    int lane = sl & 63;
    int s = (sl >> 6) & 3;
    int n = sl >> 8;
    int col = n * 16 + (lane & 15);
    int k0 = s * 32 + (lane >> 4) * 8;
    uint4 o;
    o.x = f2bf(W[(size_t)(k0 + 0) * D + col]) | (f2bf(W[(size_t)(k0 + 1) * D + col]) << 16);
    o.y = f2bf(W[(size_t)(k0 + 2) * D + col]) | (f2bf(W[(size_t)(k0 + 3) * D + col]) << 16);
    o.z = f2bf(W[(size_t)(k0 + 4) * D + col]) | (f2bf(W[(size_t)(k0 + 5) * D + col]) << 16);
    o.w = f2bf(W[(size_t)(k0 + 6) * D + col]) | (f2bf(W[(size_t)(k0 + 7) * D + col]) << 16);
    Wf[sl] = o;
    return;
  }
  // rcnts path: batch is sorted -> binary search graph boundaries
  __shared__ int bound[257];
  {
    int g = t;
    int lo = 0, hi = N_NODES;
    while (lo < hi) {
      int m = (lo + hi) >> 1;
      if (batch[m] < g) lo = m + 1; else hi = m;
    }
    bound[g] = lo;
    if (t == 255) bound[256] = N_NODES;
  }
  __syncthreads();
  int cnt = bound[t + 1] - bound[t];
  rcnts[t] = 1.0f / (float)max(cnt, 1);
}

// ---- MFMA GEMM: [N x 128] @ [128 x 128], LDS-staged A (XOR-swizzled),
//      epilogue scales row r by dinv[r]. Block = 256 thr = 64 rows. ----
template <typename TIN>
__global__ __launch_bounds__(256) void k_gemm_mfma(const TIN* __restrict__ A,
                                                   const uint4* __restrict__ Wf,
                                                   const float* __restrict__ dinv,
                                                   ushort_t* __restrict__ Out) {
  __shared__ uint4 As[1024];  // 64 rows x 16 granules (16B = 8 bf16), swizzled
  int t = threadIdx.x;
  int row0 = blockIdx.x * 64;
  if constexpr (sizeof(TIN) == 4) {  // fp32 input: 2048 float4s, coalesced
    uint2* As2 = (uint2*)As;
#pragma unroll
    for (int i = 0; i < 8; ++i) {
      int F = t + 256 * i;      // float4 id
      int r = F >> 5, f = F & 31;
      int grow = row0 + r;
      uint2 u = make_uint2(0, 0);
      if (grow < N_NODES) {
        float4 v = *(const float4*)(A + (size_t)grow * D + f * 4);
        u.x = f2bf(v.x) | (f2bf(v.y) << 16);
        u.y = f2bf(v.z) | (f2bf(v.w) << 16);
      }
      int g = f >> 1;
      As2[(r * 16 + (g ^ (r & 7))) * 2 + (f & 1)] = u;
    }
  } else {  // bf16 input: 1024 granules, coalesced 16B loads
#pragma unroll
    for (int i = 0; i < 4; ++i) {
      int G = t + 256 * i;      // granule id
      int r = G >> 4, g = G & 15;
      int grow = row0 + r;
      uint4 u = make_uint4(0, 0, 0, 0);
      if (grow < N_NODES) u = *(const uint4*)(A + (size_t)grow * D + g * 8);
      As[r * 16 + (g ^ (r & 7))] = u;
    }
  }
  __syncthreads();
  int wv = t >> 6, lane = t & 63;
  int row16 = lane & 15, chunk = lane >> 4;  // chunk 0..3
  int rl = wv * 16 + row16;
  bf16x8 afrag[4];
#pragma unroll
  for (int s = 0; s < 4; ++s) {
    int g = s * 4 + chunk;
    afrag[s] = *(const bf16x8*)&As[rl * 16 + (g ^ (rl & 7))];
  }
  f32x4 acc[8];
#pragma unroll
  for (int n = 0; n < 8; ++n) acc[n] = (f32x4){0.f, 0.f, 0.f, 0.f};
  const bf16x8* Wb = (const bf16x8*)Wf;
#pragma unroll
  for (int n = 0; n < 8; ++n) {
#pragma unroll
    for (int s = 0; s < 4; ++s) {
      bf16x8 b = Wb[(n * 4 + s) * 64 + lane];
      acc[n] = __builtin_amdgcn_mfma_f32_16x16x32_bf16(afrag[s], b, acc[n], 0, 0, 0);
    }
  }
  int row0w = row0 + wv * 16;
  int crow0 = row0w + chunk * 4;  // C/D: col=lane&15, row=(lane>>4)*4+reg
  float dv[4];
#pragma unroll
  for (int j = 0; j < 4; ++j)
    dv[j] = (crow0 + j < N_NODES) ? dinv[crow0 + j] : 0.f;
#pragma unroll
  for (int n = 0; n < 8; ++n) {
#pragma unroll
    for (int j = 0; j < 4; ++j) {
      int r = crow0 + j;
      if (r < N_NODES)
        Out[(size_t)r * D + n * 16 + row16] = (ushort_t)f2bf(acc[n][j] * dv[j]);
    }
  }
}

// ---- edge loop: wave per node, 16 edges/iter (4 groups x i32x4 of srcs) ----
// beg = node*BKT is 256B-aligned; all i32x4 reads stay inside the bucket.
__device__ __forceinline__ void agg_core(const ushort_t* __restrict__ h,
                                         const int* __restrict__ csr,
                                         int beg, int end, int grp, int d0,
                                         float* acc) {
  for (int wb = beg; wb < end; wb += 16) {
    int i0 = wb + grp * 4;
    i32x4 s4 = __builtin_nontemporal_load((const i32x4*)(csr + i0));
    bool b0 = i0 < end, b1 = i0 + 1 < end, b2 = i0 + 2 < end, b3 = i0 + 3 < end;
    uint4 v0, v1, v2, v3;
    if (b0) v0 = *(const uint4*)(h + (size_t)s4.x * D + d0);
    if (b1) v1 = *(const uint4*)(h + (size_t)s4.y * D + d0);
    if (b2) v2 = *(const uint4*)(h + (size_t)s4.z * D + d0);
    if (b3) v3 = *(const uint4*)(h + (size_t)s4.w * D + d0);
    if (b0) add8(acc, v0);
    if (b1) add8(acc, v1);
    if (b2) add8(acc, v2);
    if (b3) add8(acc, v3);
  }
}

// ---- agg layer1: wave per node; out = relu(dinv[n]*(sum+self) + b1) -> bf16 ----
__global__ __launch_bounds__(256) void k_agg_relu(const ushort_t* __restrict__ h,
                                                  const int* __restrict__ csr,
                                                  const int* __restrict__ deg,
                                                  const float* __restrict__ dinv,
                                                  const float* __restrict__ bias,
                                                  ushort_t* __restrict__ obf) {
  int t = threadIdx.x;
  int wv = t >> 6, lane = t & 63;
  int grp = lane >> 4, gl = lane & 15;
  int d0 = gl * 8;
  int node = blockIdx.x * 4 + wv;  // N_NODES % 4 == 0
  int beg = node * BKT, end = beg + min(deg[node], BKT);
  float acc[8] = {0.f, 0.f, 0.f, 0.f, 0.f, 0.f, 0.f, 0.f};
  agg_core(h, csr, beg, end, grp, d0, acc);
#pragma unroll
  for (int m = 16; m <= 32; m <<= 1) {
#pragma unroll
    for (int i = 0; i < 8; ++i) acc[i] += __shfl_xor(acc[i], m);
  }
  if (grp == 0) {
    uint4 v = *(const uint4*)(h + (size_t)node * D + d0);  // self h'
    add8(acc, v);
    float sc = dinv[node];
    float4 blo = *(const float4*)(bias + d0);
    float4 bhi = *(const float4*)(bias + d0 + 4);
    acc[0] = fmaf(acc[0], sc, blo.x);
    acc[1] = fmaf(acc[1], sc, blo.y);
    acc[2] = fmaf(acc[2], sc, blo.z);
    acc[3] = fmaf(acc[3], sc, blo.w);
    acc[4] = fmaf(acc[4], sc, bhi.x);
    acc[5] = fmaf(acc[5], sc, bhi.y);
    acc[6] = fmaf(acc[6], sc, bhi.z);
    acc[7] = fmaf(acc[7], sc, bhi.w);
#pragma unroll
    for (int i = 0; i < 8; ++i) acc[i] = fmaxf(acc[i], 0.f);
    uint4 o;
    o.x = f2bf(acc[0]) | (f2bf(acc[1]) << 16);
    o.y = f2bf(acc[2]) | (f2bf(acc[3]) << 16);
    o.z = f2bf(acc[4]) | (f2bf(acc[5]) << 16);
    o.w = f2bf(acc[6]) | (f2bf(acc[7]) << 16);
    *(uint4*)(obf + (size_t)node * D + d0) = o;
  }
}

// ---- agg layer2 + mean-pool: block = 1024 thr = 16 waves, wave per node ----
__global__ __launch_bounds__(1024) void k_agg_pool(const ushort_t* __restrict__ h,
                                                   const int* __restrict__ csr,
                                                   const int* __restrict__ deg,
                                                   const float* __restrict__ dinv,
                                                   const int* __restrict__ batch,
                                                   const float* __restrict__ rcnts,
                                                   float* __restrict__ sums) {
  __shared__ float pool2[16][128];  // 8 KB
  int t = threadIdx.x;
  int wv = t >> 6, lane = t & 63;
  int grp = lane >> 4, gl = lane & 15;
  int d0 = gl * 8;
  int node0 = blockIdx.x * 16;  // N_NODES % 16 == 0
  int node = node0 + wv;
  int g0 = batch[node0];
  int beg = node * BKT, end = beg + min(deg[node], BKT);
  float acc[8] = {0.f, 0.f, 0.f, 0.f, 0.f, 0.f, 0.f, 0.f};
  agg_core(h, csr, beg, end, grp, d0, acc);
#pragma unroll
  for (int m = 16; m <= 32; m <<= 1) {
#pragma unroll
    for (int k = 0; k < 8; ++k) acc[k] += __shfl_xor(acc[k], m);
  }
  if (grp == 0) {
    uint4 v = *(const uint4*)(h + (size_t)node * D + d0);  // self h'
    add8(acc, v);
    int g = batch[node];
    float sc = dinv[node] * rcnts[g];
    if (g == g0) {
#pragma unroll
      for (int k = 0; k < 8; ++k) pool2[wv][d0 + k] = acc[k] * sc;
    } else {
#pragma unroll
      for (int k = 0; k < 8; ++k) {
        pool2[wv][d0 + k] = 0.f;
        atomicAdd(&sums[(size_t)g * D + d0 + k], acc[k] * sc);
      }
    }
  }
  __syncthreads();
  if (t < 128) {
    float s = 0.f;
#pragma unroll
    for (int w = 0; w < 16; ++w) s += pool2[w][t];
    atomicAdd(&sums[(size_t)g0 * D + t], s);
  }
}

// ---- mean(+b2) + final linear head ----
__global__ __launch_bounds__(128) void k_final(const float* __restrict__ sums,
                                               const float* __restrict__ b2,
                                               const float* __restrict__ Wc,
                                               const float* __restrict__ bc,
                                               float* __restrict__ out) {
  __shared__ float p[128];
  int g = blockIdx.x;
  int t = threadIdx.x;
  p[t] = sums[g * D + t] + b2[t];
  __syncthreads();
  if (t < N_CLASSES) {
    float acc = bc[t];
    for (int k = 0; k < D; ++k) acc = fmaf(p[k], Wc[k * N_CLASSES + t], acc);
    out[g * N_CLASSES + t] = acc;
  }
}

extern "C" void kernel_launch(void* const* d_in, const int* in_sizes, int n_in,
                              void* d_out, int out_size, void* d_ws, size_t ws_size,
                              hipStream_t stream) {
  const float* x = (const float*)d_in[0];
  const int* ei = (const int*)d_in[1];
  const int* batch = (const int*)d_in[2];
  const float* W1 = (const float*)d_in[3];
  const float* b1 = (const float*)d_in[4];
  const float* W2 = (const float*)d_in[5];
  const float* b2 = (const float*)d_in[6];
  const float* Wc = (const float*)d_in[7];
  const float* bc = (const float*)d_in[8];
  float* out = (float*)d_out;

  char* ws = (char*)d_ws;
  size_t off = 0;
  auto alloc = [&](size_t bytes) -> void* {
    void* p = (void*)(ws + off);
    off += (bytes + 255) & ~(size_t)255;
    return p;
  };
  // zero-init region: deg, sums contiguous at the front
  int* deg = (int*)alloc((size_t)N_NODES * 4);
  float* sums = (float*)alloc((size_t)N_GRAPHS * D * 4);
  size_t zero_bytes = off;
  float* dinv = (float*)alloc((size_t)N_NODES * 4);
  float* rcnts = (float*)alloc((size_t)N_GRAPHS * 4);
  uint4* W1f = (uint4*)alloc((size_t)2048 * 16);
  uint4* W2f = (uint4*)alloc((size_t)2048 * 16);
  int* csr = (int*)alloc((size_t)N_NODES * BKT * 4);          // 12.8 MB buckets
  ushort_t* hbuf = (ushort_t*)alloc((size_t)N_NODES * D * 2);  // h' (bf16)
  ushort_t* x2 = (ushort_t*)alloc((size_t)N_NODES * D * 2);    // relu out bf16

  hipMemsetAsync(ws, 0, zero_bytes, stream);

  k_pre<<<(N_EDGES + 255) / 256, 256, 0, stream>>>(ei, deg, csr);
  k_prep<<<NB_DINV + 17, 256, 0, stream>>>(deg, dinv, W1, W2, W1f, W2f, batch, rcnts);

  k_gemm_mfma<float><<<(N_NODES + 63) / 64, 256, 0, stream>>>(x, W1f, dinv, hbuf);
  k_agg_relu<<<N_NODES / 4, 256, 0, stream>>>(hbuf, csr, deg, dinv, b1, x2);
  k_gemm_mfma<ushort_t><<<(N_NODES + 63) / 64, 256, 0, stream>>>(x2, W2f, dinv, hbuf);
  k_agg_pool<<<N_NODES / 16, 1024, 0, stream>>>(hbuf, csr, deg, dinv, batch, rcnts, sums);

  k_final<<<N_GRAPHS, 128, 0, stream>>>(sums, b2, Wc, bc, out);
}